// Round 14
// baseline (87.018 us; speedup 1.0000x reference)
//
#include <hip/hip_runtime.h>
#include <hip/hip_bf16.h>

typedef float f32x4 __attribute__((ext_vector_type(4)));
typedef __bf16 bf16x8 __attribute__((ext_vector_type(8)));

#define INF   8192             // in_features
#define FOLDS 127
#define LOCAL 128
#define OUTF  (FOLDS * LOCAL)  // 16256
#define BM    64               // batch rows per tile
#define BN    64               // output features per block (half a fold)
#define NT    4                // batch tiles per block (reg-prefetch pipeline)

// As/Bs: 64 rows x 128 cols bf16 (row stride 256B), XOR swizzle byte ^= (row&7)<<4
__device__ __forceinline__ void cvt_store8(char* lds, int byte, f32x4 v0, f32x4 v1) {
    bf16x8 w;
    w[0] = (__bf16)v0[0]; w[1] = (__bf16)v0[1]; w[2] = (__bf16)v0[2]; w[3] = (__bf16)v0[3];
    w[4] = (__bf16)v1[0]; w[5] = (__bf16)v1[1]; w[6] = (__bf16)v1[2]; w[7] = (__bf16)v1[3];
    *(bf16x8*)(lds + byte) = w;
}

__global__ __launch_bounds__(256, 5)   // 32 KB LDS -> 5 blocks/CU, 20 waves/CU
void local_linear_kernel(const float* __restrict__ x,
                         const float* __restrict__ W,
                         const float* __restrict__ bias,
                         float* __restrict__ out)
{
    __shared__ __align__(16) __bf16 As[BM * 128];   // x tile, 16 KiB (rotated through NT tiles)
    __shared__ __align__(16) __bf16 Bs[BN * 128];   // W half-fold, 16 KiB (persistent)

    const int mt4 = blockIdx.x;         // 256-row group 0..7
    const int fn  = blockIdx.y;         // fold-half 0..253
    const int f   = fn >> 1;            // fold 0..126
    const int bn0 = (fn & 1) * BN;      // 0 or 64
    const int t   = threadIdx.x;        // 0..255

    const int m0   = mt4 * NT * BM;     // tile tt rows: m0 + tt*64
    const int lane = t & 63;
    const int wid  = t >> 6;
    const int wm   = wid >> 1;   // 0..1 (32 batch rows each)
    const int wn   = wid & 1;    // 0..1 (32 features each)
    const int r16  = lane & 15;
    const int kq   = lane >> 4;  // 0..3

    // ---- stage W half-fold -> Bs (once per block) ----
    const float* __restrict__ Wf = W + (size_t)f * (LOCAL * 128) + (size_t)bn0 * 128;
    #pragma unroll
    for (int it = 0; it < 4; ++it) {
        const int e = it * 2048 + t * 8;
        const int row = e >> 7, col = e & 127;
        const float* g = Wf + row * 128 + col;
        f32x4 v0 = *(const f32x4*)g;
        f32x4 v1 = *(const f32x4*)(g + 4);
        cvt_store8((char*)Bs, (row * 256 + col * 2) ^ ((row & 7) << 4), v0, v1);
    }

    // ---- stage x tile0 -> As ----
    const float* __restrict__ xg = x + (size_t)m0 * INF + (size_t)f * 64;
    #pragma unroll
    for (int it = 0; it < 4; ++it) {
        const int e = it * 2048 + t * 8;
        const int row = e >> 7, col = e & 127;
        const float* g = xg + (size_t)row * INF + col;
        f32x4 v0 = *(const f32x4*)g;
        f32x4 v1 = *(const f32x4*)(g + 4);
        cvt_store8((char*)As, (row * 256 + col * 2) ^ ((row & 7) << 4), v0, v1);
    }

    // bias (n dim) -> acc init
    float bv[2];
    #pragma unroll
    for (int j = 0; j < 2; ++j)
        bv[j] = bias[f * LOCAL + bn0 + wn * 32 + j * 16 + r16];

    __syncthreads();   // full drain once: Bs + As(tile0) visible, vmcnt = 0

    // ---- pipelined tile loop: prefetch t+1 into regs under compute/store of t ----
    #pragma unroll
    for (int tt = 0; tt < NT; ++tt) {
        f32x4 pre[8];
        if (tt + 1 < NT) {
            const float* __restrict__ xgn = xg + (size_t)(tt + 1) * BM * INF;
            #pragma unroll
            for (int it = 0; it < 4; ++it) {
                const int e = it * 2048 + t * 8;
                const int row = e >> 7, col = e & 127;
                const float* g = xgn + (size_t)row * INF + col;
                pre[it * 2 + 0] = *(const f32x4*)g;
                pre[it * 2 + 1] = *(const f32x4*)(g + 4);
            }
            __builtin_amdgcn_sched_barrier(0);   // pin load issue before compute
        }

        // ---- compute tile tt ----
        f32x4 acc[2][2];
        #pragma unroll
        for (int i = 0; i < 2; ++i)
            #pragma unroll
            for (int j = 0; j < 2; ++j)
                acc[i][j] = (f32x4){bv[j], bv[j], bv[j], bv[j]};

        #pragma unroll
        for (int ks = 0; ks < 4; ++ks) {
            const int kof = ks * 32 + kq * 8;
            bf16x8 a[2], b[2];
            #pragma unroll
            for (int i = 0; i < 2; ++i) {
                const int row  = wm * 32 + i * 16 + r16;
                const int byte = (row * 256 + kof * 2) ^ ((row & 7) << 4);
                a[i] = *(const bf16x8*)((const char*)As + byte);
            }
            #pragma unroll
            for (int j = 0; j < 2; ++j) {
                const int row  = wn * 32 + j * 16 + r16;
                const int byte = (row * 256 + kof * 2) ^ ((row & 7) << 4);
                b[j] = *(const bf16x8*)((const char*)Bs + byte);
            }
            #pragma unroll
            for (int i = 0; i < 2; ++i)
                #pragma unroll
                for (int j = 0; j < 2; ++j)
                    acc[i][j] = __builtin_amdgcn_mfma_f32_16x16x32_bf16(a[i], b[j], acc[i][j], 0, 0, 0);
        }

        // ---- store tile tt (16 dword stores, left in flight) ----
        #pragma unroll
        for (int i = 0; i < 2; ++i) {
            const int mrow = m0 + tt * BM + wm * 32 + i * 16 + kq * 4;  // C/D: m = kq*4+reg
            #pragma unroll
            for (int j = 0; j < 2; ++j) {
                const int ncol = f * LOCAL + bn0 + wn * 32 + j * 16 + r16;  // n = lane&15
                float* o = out + (size_t)mrow * OUTF + ncol;
                #pragma unroll
                for (int r = 0; r < 4; ++r)
                    o[(size_t)r * OUTF] = acc[i][j][r];
            }
        }

        if (tt + 1 < NT) {
            __builtin_amdgcn_sched_barrier(0);
            __builtin_amdgcn_s_barrier();                      // all waves done reading As
            // outstanding (oldest->newest): [stores tt-1 (<=16)] [pre 8] [stores tt 16]
            // vmcnt(16) retires everything except the 16 newest -> pre[] has landed.
            asm volatile("s_waitcnt vmcnt(16)" ::: "memory");
            __builtin_amdgcn_sched_barrier(0);
            #pragma unroll
            for (int it = 0; it < 4; ++it) {
                const int e = it * 2048 + t * 8;
                const int row = e >> 7, col = e & 127;
                cvt_store8((char*)As, (row * 256 + col * 2) ^ ((row & 7) << 4),
                           pre[it * 2 + 0], pre[it * 2 + 1]);
            }
            asm volatile("s_waitcnt lgkmcnt(0)" ::: "memory");
            __builtin_amdgcn_s_barrier();                      // As(tile tt+1) ready
            __builtin_amdgcn_sched_barrier(0);
        }
    }
}

extern "C" void kernel_launch(void* const* d_in, const int* in_sizes, int n_in,
                              void* d_out, int out_size, void* d_ws, size_t ws_size,
                              hipStream_t stream) {
    const float* x    = (const float*)d_in[0];
    const float* W    = (const float*)d_in[1];
    const float* bias = (const float*)d_in[2];
    float* out        = (float*)d_out;

    dim3 grid(2048 / (NT * BM), FOLDS * 2);   // 8 x 254 = 2032 blocks, mt fast
    dim3 block(256);
    local_linear_kernel<<<grid, block, 0, stream>>>(x, W, bias, out);
}

// Round 15
// 44.941 us; speedup vs baseline: 1.9363x; 1.9363x over previous
//
#include <hip/hip_runtime.h>
#include <hip/hip_bf16.h>

typedef float f32x4 __attribute__((ext_vector_type(4)));
typedef __bf16 bf16x8 __attribute__((ext_vector_type(8)));

#define INF   8192             // in_features
#define FOLDS 127
#define LOCAL 128
#define OUTF  (FOLDS * LOCAL)  // 16256
#define BM    64               // batch rows per tile
#define BN    64               // output features per block (half a fold)

// As/Bs: 64 rows x 128 cols bf16 (row stride 256B), XOR swizzle byte ^= (row&7)<<4
__device__ __forceinline__ void cvt_store8(char* lds, int byte, f32x4 v0, f32x4 v1) {
    bf16x8 w;
    w[0] = (__bf16)v0[0]; w[1] = (__bf16)v0[1]; w[2] = (__bf16)v0[2]; w[3] = (__bf16)v0[3];
    w[4] = (__bf16)v1[0]; w[5] = (__bf16)v1[1]; w[6] = (__bf16)v1[2]; w[7] = (__bf16)v1[3];
    *(bf16x8*)(lds + byte) = w;
}

__global__ __launch_bounds__(512, 8)   // 8 waves/SIMD requested -> VGPR<=64; 32KB LDS -> 4 blocks/CU = 32 waves/CU (full)
void local_linear_kernel(const float* __restrict__ x,
                         const float* __restrict__ W,
                         const float* __restrict__ bias,
                         float* __restrict__ out)
{
    __shared__ __align__(16) __bf16 As[BM * 128];   // x tile, 16 KiB (reused for tile 1)
    __shared__ __align__(16) __bf16 Bs[BN * 128];   // W half-fold, 16 KiB (persistent)

    const int mt2 = blockIdx.x;         // 128-row group 0..15 (16-wide fast dim: keep R13's XCD geometry)
    const int fn  = blockIdx.y;         // fold-half 0..253
    const int f   = fn >> 1;            // fold 0..126
    const int bn0 = (fn & 1) * BN;      // 0 or 64
    const int t   = threadIdx.x;        // 0..511

    const int m0   = mt2 * 2 * BM;      // tile0 rows m0.., tile1 rows m0+64..
    const int lane = t & 63;
    const int wid  = t >> 6;     // 0..7
    const int wm   = wid >> 2;   // 0..1 (32 batch rows each)
    const int wn   = wid & 3;    // 0..3 (16 features each)
    const int r16  = lane & 15;
    const int kq   = lane >> 4;  // 0..3

    // ---- stage W half-fold -> Bs (once per block): 8192 floats, 2 iters ----
    const float* __restrict__ Wf = W + (size_t)f * (LOCAL * 128) + (size_t)bn0 * 128;
    #pragma unroll
    for (int it = 0; it < 2; ++it) {
        const int e = it * 4096 + t * 8;
        const int row = e >> 7, col = e & 127;
        const float* g = Wf + row * 128 + col;
        f32x4 v0 = *(const f32x4*)g;
        f32x4 v1 = *(const f32x4*)(g + 4);
        cvt_store8((char*)Bs, (row * 256 + col * 2) ^ ((row & 7) << 4), v0, v1);
    }

    // ---- stage x tile0 -> As ----
    const float* __restrict__ xg = x + (size_t)m0 * INF + (size_t)f * 64;
    #pragma unroll
    for (int it = 0; it < 2; ++it) {
        const int e = it * 4096 + t * 8;
        const int row = e >> 7, col = e & 127;
        const float* g = xg + (size_t)row * INF + col;
        f32x4 v0 = *(const f32x4*)g;
        f32x4 v1 = *(const f32x4*)(g + 4);
        cvt_store8((char*)As, (row * 256 + col * 2) ^ ((row & 7) << 4), v0, v1);
    }

    // bias (n dim, 16 feats per wave) -> acc init
    const float bv = bias[f * LOCAL + bn0 + wn * 16 + r16];

    __syncthreads();   // full drain once: Bs + As(tile0) visible, vmcnt = 0

    // ---- prefetch tile1 into REGISTERS (4 dwordx4 loads, in flight across tile0) ----
    f32x4 pre[4];
    {
        const float* __restrict__ xg1 = xg + (size_t)BM * INF;
        #pragma unroll
        for (int it = 0; it < 2; ++it) {
            const int e = it * 4096 + t * 8;
            const int row = e >> 7, col = e & 127;
            const float* g = xg1 + (size_t)row * INF + col;
            pre[it * 2 + 0] = *(const f32x4*)g;
            pre[it * 2 + 1] = *(const f32x4*)(g + 4);
        }
    }
    __builtin_amdgcn_sched_barrier(0);   // pin load issue here

    // ================= tile 0: compute + store =================
    {
        f32x4 acc[2];
        #pragma unroll
        for (int i = 0; i < 2; ++i)
            acc[i] = (f32x4){bv, bv, bv, bv};

        #pragma unroll
        for (int ks = 0; ks < 4; ++ks) {
            const int kof = ks * 32 + kq * 8;
            bf16x8 a[2], b;
            #pragma unroll
            for (int i = 0; i < 2; ++i) {
                const int row  = wm * 32 + i * 16 + r16;
                const int byte = (row * 256 + kof * 2) ^ ((row & 7) << 4);
                a[i] = *(const bf16x8*)((const char*)As + byte);
            }
            {
                const int row  = wn * 16 + r16;
                const int byte = (row * 256 + kof * 2) ^ ((row & 7) << 4);
                b = *(const bf16x8*)((const char*)Bs + byte);
            }
            #pragma unroll
            for (int i = 0; i < 2; ++i)
                acc[i] = __builtin_amdgcn_mfma_f32_16x16x32_bf16(a[i], b, acc[i], 0, 0, 0);
        }

        #pragma unroll
        for (int i = 0; i < 2; ++i) {
            const int mrow = m0 + wm * 32 + i * 16 + kq * 4;   // C/D: m = kq*4 + reg
            const int ncol = f * LOCAL + bn0 + wn * 16 + r16;  // n = lane&15
            float* o = out + (size_t)mrow * OUTF + ncol;
            #pragma unroll
            for (int r = 0; r < 4; ++r)
                o[(size_t)r * OUTF] = acc[i][r];               // 8 stores total, left in flight
        }
    }

    // ================= swap As to tile1 (stores stay in flight) =================
    __builtin_amdgcn_sched_barrier(0);
    __builtin_amdgcn_s_barrier();                     // all waves done reading As
    // outstanding: pre(4) then stores(8). vmcnt(8) retires pre, leaves stores flying.
    asm volatile("s_waitcnt vmcnt(8)" ::: "memory");
    __builtin_amdgcn_sched_barrier(0);
    #pragma unroll
    for (int it = 0; it < 2; ++it) {
        const int e = it * 4096 + t * 8;
        const int row = e >> 7, col = e & 127;
        cvt_store8((char*)As, (row * 256 + col * 2) ^ ((row & 7) << 4),
                   pre[it * 2 + 0], pre[it * 2 + 1]);
    }
    asm volatile("s_waitcnt lgkmcnt(0)" ::: "memory");
    __builtin_amdgcn_s_barrier();                     // As(tile1) ready
    __builtin_amdgcn_sched_barrier(0);

    // ================= tile 1: compute + store =================
    {
        const int m1 = m0 + BM;
        f32x4 acc[2];
        #pragma unroll
        for (int i = 0; i < 2; ++i)
            acc[i] = (f32x4){bv, bv, bv, bv};

        #pragma unroll
        for (int ks = 0; ks < 4; ++ks) {
            const int kof = ks * 32 + kq * 8;
            bf16x8 a[2], b;
            #pragma unroll
            for (int i = 0; i < 2; ++i) {
                const int row  = wm * 32 + i * 16 + r16;
                const int byte = (row * 256 + kof * 2) ^ ((row & 7) << 4);
                a[i] = *(const bf16x8*)((const char*)As + byte);
            }
            {
                const int row  = wn * 16 + r16;
                const int byte = (row * 256 + kof * 2) ^ ((row & 7) << 4);
                b = *(const bf16x8*)((const char*)Bs + byte);
            }
            #pragma unroll
            for (int i = 0; i < 2; ++i)
                acc[i] = __builtin_amdgcn_mfma_f32_16x16x32_bf16(a[i], b, acc[i], 0, 0, 0);
        }

        #pragma unroll
        for (int i = 0; i < 2; ++i) {
            const int mrow = m1 + wm * 32 + i * 16 + kq * 4;
            const int ncol = f * LOCAL + bn0 + wn * 16 + r16;
            float* o = out + (size_t)mrow * OUTF + ncol;
            #pragma unroll
            for (int r = 0; r < 4; ++r)
                o[(size_t)r * OUTF] = acc[i][r];
        }
    }
}

extern "C" void kernel_launch(void* const* d_in, const int* in_sizes, int n_in,
                              void* d_out, int out_size, void* d_ws, size_t ws_size,
                              hipStream_t stream) {
    const float* x    = (const float*)d_in[0];
    const float* W    = (const float*)d_in[1];
    const float* bias = (const float*)d_in[2];
    float* out        = (float*)d_out;

    dim3 grid(2048 / (2 * BM), FOLDS * 2);   // 16 x 254 = 4064 blocks, mt fast (R13 geometry)
    dim3 block(512);
    local_linear_kernel<<<grid, block, 0, stream>>>(x, W, bias, out);
}